// Round 12
// baseline (854.252 us; speedup 1.0000x reference)
//
#include <hip/hip_runtime.h>
#include <hip/hip_bf16.h>
#include <math.h>

#define D_MODEL 768
#define T_SEQ   1024
#define BATCH   4
#define NCH     7
#define ROWS    4096            // BATCH*T_SEQ
#define KM      (NCH * D_MODEL) // 5376

typedef unsigned short u16;
typedef __attribute__((ext_vector_type(8))) short bh8;   // 8 x bf16
typedef __attribute__((ext_vector_type(4))) float f32x4;

__device__ __forceinline__ u16 f2bf(float f) {
    union { float f; unsigned u; } v; v.f = f;
    return (u16)((v.u + 0x7fffu + ((v.u >> 16) & 1u)) >> 16);  // RNE
}
__device__ __forceinline__ float bf2f(u16 b) {
    union { unsigned u; float f; } v; v.u = ((unsigned)b) << 16;
    return v.f;
}
__device__ __forceinline__ float wred_sum(float v) {
    #pragma unroll
    for (int o = 32; o; o >>= 1) v += __shfl_down(v, o, 64);
    return v;
}
__device__ __forceinline__ float wred_max(float v) {
    #pragma unroll
    for (int o = 32; o; o >>= 1) v = fmaxf(v, __shfl_down(v, o, 64));
    return v;
}
__device__ __forceinline__ float chamber_mask(int i) {
    float slope = 8.0f * 7.0f / 2000.0f;
    return 1.0f / (1.0f + __expf(-slope * (4000.0f - 2000.0f * (i + 0.5f) / 7.0f)));
}

#define GLD16(g, l) __builtin_amdgcn_global_load_lds( \
    (const __attribute__((address_space(1))) void*)(g), \
    (__attribute__((address_space(3))) void*)(l), 16, 0, 0)

// XCD-aware swizzle: each XCD gets a contiguous tile range under round-robin
// dispatch -> L2 reuse of shared A-tiles / z-slabs. Identity if N % 8 != 0.
__device__ __forceinline__ int xcd_swizzle(int gflat, int Ntot) {
    if ((Ntot & 7) == 0) {
        int chunk = Ntot >> 3;
        gflat = (gflat & 7) * chunk + (gflat >> 3);
    }
    return gflat;
}

// ---------------------------------------------------------------------------
// 128x128-tile NT GEMM: C = alpha * A[M,K] * B[N,K]^T  (bf16 in)
// K=64 per barrier as TWO BK=32 panels; XCD tile swizzle.
// mode: 0 f32 store, 1 bf16 store, 3 f16 store
// kss/klen: K slice per bz1 (merge partials).
// ---------------------------------------------------------------------------
__global__ __launch_bounds__(256)
void gemm_nt_kernel(const u16* __restrict__ A, const u16* __restrict__ B,
                    void* __restrict__ Cv,
                    int K, int lda, int ldb, int ldc,
                    long long sA1, long long sA2, long long sB1, long long sB2,
                    long long sC1, long long sC2, int zm,
                    float alpha, int mode, int causal_skip, int causal_k,
                    int kss, int klen)
{
    int gx = gridDim.x, gy = gridDim.y;
    int Ntot = gx * gy * gridDim.z;
    int gflat = xcd_swizzle(blockIdx.x + gx * (blockIdx.y + gy * blockIdx.z), Ntot);
    int bn = gflat % gx;
    int rest = gflat / gx;
    int bm = rest % gy;
    int bz = rest / gy;
    if (causal_skip && bn > bm) return;
    int bz1 = bz % zm, bz2 = bz / zm;

    const u16* Ab = A + bz1 * sA1 + bz2 * sA2 + (long long)(bm * 128) * lda;
    const u16* Bb = B + bz1 * sB1 + bz2 * sB2 + (long long)(bn * 128) * ldb;

    __shared__ u16 sm[4 * 128 * 32];   // 32 KB: A0|B0|A1|B1
    u16* Al0 = sm;
    u16* Bl0 = sm + 128 * 32;
    u16* Al1 = sm + 2 * 128 * 32;
    u16* Bl1 = sm + 3 * 128 * 32;

    int tid  = threadIdx.x;
    int lane = tid & 63;
    int wave = tid >> 6;
    int wm = wave >> 1, wn = wave & 1;

    int k_begin = kss ? bz1 * kss : 0;
    int k_end   = klen ? (k_begin + klen) : K;
    if (causal_k) k_end = min(k_end, (bm + 1) * 128);

    f32x4 acc[4][4];
    #pragma unroll
    for (int i = 0; i < 4; i++)
        #pragma unroll
        for (int j = 0; j < 4; j++)
            acc[i][j] = (f32x4){0.f, 0.f, 0.f, 0.f};

    int srow = lane >> 2;
    int skq  = (lane & 3) * 8;
    int fm   = lane & 15;
    int fk   = (lane >> 4) * 8;

    for (int k0 = k_begin; k0 < k_end; k0 += 64) {
        __syncthreads();
        #pragma unroll
        for (int r = 0; r < 2; r++) {
            int row = r * 64 + wave * 16 + srow;
            long long ra = (long long)row * lda + k0 + skq;
            long long rb2 = (long long)row * ldb + k0 + skq;
            GLD16(Ab + ra,       Al0 + row * 32 + skq);
            GLD16(Bb + rb2,      Bl0 + row * 32 + skq);
            GLD16(Ab + ra + 32,  Al1 + row * 32 + skq);
            GLD16(Bb + rb2 + 32, Bl1 + row * 32 + skq);
        }
        __syncthreads();

        #pragma unroll
        for (int p = 0; p < 2; p++) {
            const u16* Al = p ? Al1 : Al0;
            const u16* Bl = p ? Bl1 : Bl0;
            bh8 af[4], bf[4];
            #pragma unroll
            for (int i = 0; i < 4; i++)
                af[i] = *(const bh8*)(Al + (wm * 64 + i * 16 + fm) * 32 + fk);
            #pragma unroll
            for (int j = 0; j < 4; j++)
                bf[j] = *(const bh8*)(Bl + (wn * 64 + j * 16 + fm) * 32 + fk);
            #pragma unroll
            for (int i = 0; i < 4; i++)
                #pragma unroll
                for (int j = 0; j < 4; j++)
                    acc[i][j] = __builtin_amdgcn_mfma_f32_16x16x32_bf16(af[i], bf[j], acc[i][j], 0, 0, 0);
        }
    }

    int rbase = bm * 128 + wm * 64 + (lane >> 4) * 4;
    int cbase = bn * 128 + wn * 64 + (lane & 15);
    long long zoff = bz1 * sC1 + bz2 * sC2;
    if (mode == 1) {
        u16* C = (u16*)Cv + zoff;
        #pragma unroll
        for (int i = 0; i < 4; i++)
            #pragma unroll
            for (int j = 0; j < 4; j++)
                #pragma unroll
                for (int r = 0; r < 4; r++)
                    C[(long long)(rbase + i * 16 + r) * ldc + cbase + j * 16] = f2bf(acc[i][j][r] * alpha);
    } else if (mode == 3) {
        u16* C = (u16*)Cv + zoff;
        #pragma unroll
        for (int i = 0; i < 4; i++)
            #pragma unroll
            for (int j = 0; j < 4; j++)
                #pragma unroll
                for (int r = 0; r < 4; r++) {
                    union { _Float16 h; u16 u; } cv;
                    cv.h = (_Float16)(acc[i][j][r] * alpha);
                    C[(long long)(rbase + i * 16 + r) * ldc + cbase + j * 16] = cv.u;
                }
    } else {
        float* C = (float*)Cv + zoff;
        #pragma unroll
        for (int i = 0; i < 4; i++)
            #pragma unroll
            for (int j = 0; j < 4; j++)
                #pragma unroll
                for (int r = 0; r < 4; r++)
                    C[(long long)(rbase + i * 16 + r) * ldc + cbase + j * 16] = acc[i][j][r] * alpha;
    }
}

// ---------------------------------------------------------------------------
// 64x64-tile NT GEMM — par-branch batched launches. K=128 as 4 BK=32 panels.
// mode: 0 f32, 1 bf16, 3 f16,
//       5 par PV+delta: db[(bz1,t)][bz2*768+d] = bf16(coef*(acc - h))
// ---------------------------------------------------------------------------
__global__ __launch_bounds__(256)
void gemm64_nt_kernel(const u16* __restrict__ A, const u16* __restrict__ B,
                      void* __restrict__ Cv,
                      int K, int lda, int ldb, int ldc,
                      long long sA1, long long sA2, long long sB1, long long sB2,
                      long long sC1, long long sC2, int zm,
                      float alpha, int mode, int causal_skip, int causal_k,
                      const float* __restrict__ coefp,
                      const float* __restrict__ hp, u16* __restrict__ dbp)
{
    int gx = gridDim.x, gy = gridDim.y;
    int Ntot = gx * gy * gridDim.z;
    int gflat = xcd_swizzle(blockIdx.x + gx * (blockIdx.y + gy * blockIdx.z), Ntot);
    int bn = gflat % gx;
    int rest = gflat / gx;
    int bm = rest % gy;
    int bz = rest / gy;
    if (causal_skip && bn > bm) return;
    int bz1 = bz % zm, bz2 = bz / zm;

    const u16* Ab = A + bz1 * sA1 + bz2 * sA2 + (long long)(bm * 64) * lda;
    const u16* Bb = B + bz1 * sB1 + bz2 * sB2 + (long long)(bn * 64) * ldb;

    __shared__ u16 sm[8 * 64 * 32];    // 32 KB: A0 B0 .. A3 B3
    const int PS = 64 * 32;

    int tid  = threadIdx.x;
    int lane = tid & 63;
    int wave = tid >> 6;

    int k_end = causal_k ? min(K, (bm + 1) * 64) : K;

    f32x4 acc[4];
    #pragma unroll
    for (int j = 0; j < 4; j++) acc[j] = (f32x4){0.f, 0.f, 0.f, 0.f};

    int srow   = tid >> 2;
    int schunk = (tid & 3) * 8;
    int fm     = lane & 15;
    int fk     = (lane >> 4) * 8;

    int k0 = 0;
    while (k0 < k_end) {
        __syncthreads();
        int np = (k_end - k0 >= 128) ? 4 : 2;
        for (int p = 0; p < np; p++) {
            long long ra  = (long long)srow * lda + k0 + p * 32 + schunk;
            long long rb2 = (long long)srow * ldb + k0 + p * 32 + schunk;
            GLD16(Ab + ra,  sm + (2 * p) * PS + srow * 32 + schunk);
            GLD16(Bb + rb2, sm + (2 * p + 1) * PS + srow * 32 + schunk);
        }
        __syncthreads();
        for (int p = 0; p < np; p++) {
            const u16* Al = sm + (2 * p) * PS;
            const u16* Bl = sm + (2 * p + 1) * PS;
            bh8 af = *(const bh8*)(Al + (wave * 16 + fm) * 32 + fk);
            bh8 bf[4];
            #pragma unroll
            for (int j = 0; j < 4; j++)
                bf[j] = *(const bh8*)(Bl + (j * 16 + fm) * 32 + fk);
            #pragma unroll
            for (int j = 0; j < 4; j++)
                acc[j] = __builtin_amdgcn_mfma_f32_16x16x32_bf16(af, bf[j], acc[j], 0, 0, 0);
        }
        k0 += np * 32;
    }

    int rbase = bm * 64 + wave * 16 + (lane >> 4) * 4;
    int cbase = bn * 64 + (lane & 15);
    long long zoff = bz1 * sC1 + bz2 * sC2;
    if (mode == 1) {
        u16* C = (u16*)Cv + zoff;
        #pragma unroll
        for (int j = 0; j < 4; j++)
            #pragma unroll
            for (int r = 0; r < 4; r++)
                C[(long long)(rbase + r) * ldc + cbase + j * 16] = f2bf(acc[j][r] * alpha);
    } else if (mode == 3) {
        u16* C = (u16*)Cv + zoff;
        #pragma unroll
        for (int j = 0; j < 4; j++)
            #pragma unroll
            for (int r = 0; r < 4; r++) {
                union { _Float16 h; u16 u; } cv;
                cv.h = (_Float16)(acc[j][r] * alpha);
                C[(long long)(rbase + r) * ldc + cbase + j * 16] = cv.u;
            }
    } else if (mode == 5) {
        int b = bz1, ch = bz2;
        #pragma unroll
        for (int r = 0; r < 4; r++) {
            int t = rbase + r;
            long long rowg = (long long)b * T_SEQ + t;
            float cf = coefp[(long long)ch * ROWS + rowg];
            #pragma unroll
            for (int j = 0; j < 4; j++) {
                int d = cbase + j * 16;
                float hv = hp[rowg * D_MODEL + d];
                dbp[rowg * KM + ch * D_MODEL + d] = f2bf(cf * (acc[j][r] - hv));
            }
        }
    } else {
        float* C = (float*)Cv + zoff;
        #pragma unroll
        for (int j = 0; j < 4; j++)
            #pragma unroll
            for (int r = 0; r < 4; r++)
                C[(long long)(rbase + r) * ldc + cbase + j * 16] = acc[j][r] * alpha;
    }
}

// ---------------------------------------------------------------------------
// 32x64-tile NT GEMM — for the grid-starved SEQ chain (2x the block count of
// the 64-tile). 4 waves: wm=wave&1 row-frag, wn=wave>>1 col-half.
// K=128 as 4 BK=32 panels (2-panel tail). 24 KB LDS -> 6 blocks/CU.
// causal_skip: skip iff bn*64 > bm*32+31 (softmax masks partial tiles).
// causal_k: K <= bm*32+32 rounded up to 64 (P zeros above diagonal).
// mode: 1 bf16, 3 f16,
//       6 seq PV+delta: hh' = hh + coef*(acc - hh) -> hhf, hbs, hts(transposed)
// ---------------------------------------------------------------------------
__global__ __launch_bounds__(256)
void gemm32_nt_kernel(const u16* __restrict__ A, const u16* __restrict__ B,
                      void* __restrict__ Cv,
                      int K, int lda, int ldb, int ldc,
                      long long sA1, long long sB1, long long sC1, int zm,
                      float alpha, int mode, int causal_skip, int causal_k,
                      float* __restrict__ hhfp, const float* __restrict__ coefp,
                      u16* __restrict__ hbsp, u16* __restrict__ htsp)
{
    int gx = gridDim.x, gy = gridDim.y;
    int Ntot = gx * gy * gridDim.z;
    int gflat = xcd_swizzle(blockIdx.x + gx * (blockIdx.y + gy * blockIdx.z), Ntot);
    int bn = gflat % gx;
    int rest = gflat / gx;
    int bm = rest % gy;
    int bz1 = rest / gy;                    // batch (zm slabs)
    (void)zm;
    if (causal_skip && bn * 64 > bm * 32 + 31) return;

    const u16* Ab = A + bz1 * sA1 + (long long)(bm * 32) * lda;
    const u16* Bb = B + bz1 * sB1 + (long long)(bn * 64) * ldb;

    __shared__ u16 sm[4 * 96 * 32];         // 24 KB: 4 panels of (A 32x32 | B 64x32)
    const int PS = 96 * 32;                 // 3072 u16 per panel

    int tid  = threadIdx.x;
    int lane = tid & 63;
    int wave = tid >> 6;
    int wm = wave & 1, wn = wave >> 1;

    int k_end = K;
    if (causal_k) {
        int ke = bm * 32 + 32;
        ke = (ke + 63) & ~63;               // round up; P is zero above diagonal
        k_end = min(K, ke);
    }

    f32x4 acc[2];
    acc[0] = (f32x4){0.f, 0.f, 0.f, 0.f};
    acc[1] = (f32x4){0.f, 0.f, 0.f, 0.f};

    int srow   = tid >> 2;                  // B: 0..63 ; A (tid<128): 0..31
    int schunk = (tid & 3) * 8;
    int fm     = lane & 15;
    int fk     = (lane >> 4) * 8;

    int k0 = 0;
    while (k0 < k_end) {
        __syncthreads();
        int np = (k_end - k0 >= 128) ? 4 : 2;
        for (int p = 0; p < np; p++) {
            if (tid < 128)
                GLD16(Ab + (long long)srow * lda + k0 + p * 32 + schunk,
                      sm + p * PS + srow * 32 + schunk);
            GLD16(Bb + (long long)srow * ldb + k0 + p * 32 + schunk,
                  sm + p * PS + 32 * 32 + srow * 32 + schunk);
        }
        __syncthreads();
        for (int p = 0; p < np; p++) {
            const u16* Al = sm + p * PS;
            const u16* Bl = sm + p * PS + 32 * 32;
            bh8 af = *(const bh8*)(Al + (wm * 16 + fm) * 32 + fk);
            bh8 bf[2];
            #pragma unroll
            for (int j = 0; j < 2; j++)
                bf[j] = *(const bh8*)(Bl + (wn * 32 + j * 16 + fm) * 32 + fk);
            #pragma unroll
            for (int j = 0; j < 2; j++)
                acc[j] = __builtin_amdgcn_mfma_f32_16x16x32_bf16(af, bf[j], acc[j], 0, 0, 0);
        }
        k0 += np * 32;
    }

    int rbase = bm * 32 + wm * 16 + (lane >> 4) * 4;   // global row (within slab)
    int cbase = bn * 64 + wn * 32 + (lane & 15);       // global col
    long long zoff = bz1 * sC1;
    if (mode == 1) {
        u16* C = (u16*)Cv + zoff;
        #pragma unroll
        for (int j = 0; j < 2; j++)
            #pragma unroll
            for (int r = 0; r < 4; r++)
                C[(long long)(rbase + r) * ldc + cbase + j * 16] = f2bf(acc[j][r] * alpha);
    } else if (mode == 3) {
        u16* C = (u16*)Cv + zoff;
        #pragma unroll
        for (int j = 0; j < 2; j++)
            #pragma unroll
            for (int r = 0; r < 4; r++) {
                union { _Float16 h; u16 u; } cv;
                cv.h = (_Float16)(acc[j][r] * alpha);
                C[(long long)(rbase + r) * ldc + cbase + j * 16] = cv.u;
            }
    } else if (mode == 6) {
        __syncthreads();                    // staging dead; reuse sm as tile
        u16* tile = sm;                     // [64 d][34] stride
        #pragma unroll
        for (int r = 0; r < 4; r++) {
            int t = rbase + r;              // 0..1023
            long long rowg = (long long)bz1 * T_SEQ + t;
            float cf = coefp[rowg];
            int tl = t - bm * 32;           // 0..31
            #pragma unroll
            for (int j = 0; j < 2; j++) {
                int d = cbase + j * 16;     // 0..767 (block covers bn*64..+63)
                long long idx = rowg * D_MODEL + d;
                float v = hhfp[idx];
                float nh = v + cf * (acc[j][r] - v);
                hhfp[idx] = nh;
                u16 w = f2bf(nh);
                hbsp[idx] = w;
                int dl = d - bn * 64;       // 0..63
                tile[dl * 34 + tl] = w;
            }
        }
        __syncthreads();
        int dl = tid >> 2, tt = (tid & 3) * 8;
        long long ob = (long long)bz1 * T_SEQ * D_MODEL +
                       (long long)(bn * 64 + dl) * T_SEQ + bm * 32 + tt;
        #pragma unroll
        for (int kk = 0; kk < 8; kk++)
            htsp[ob + kk] = tile[dl * 34 + tt + kk];
    }
}

// ---------------------------------------------------------------------------
// LN pre: h = LN(x)*g+b; hhf = h; hbp = hbs = bf16(h)
// ---------------------------------------------------------------------------
__global__ __launch_bounds__(256)
void ln_pre_kernel(const float* __restrict__ x, const float* __restrict__ g,
                   const float* __restrict__ b, float* __restrict__ h,
                   float* __restrict__ hhf, u16* __restrict__ hbp,
                   u16* __restrict__ hbs)
{
    int row = blockIdx.x;
    long long base = (long long)row * D_MODEL;
    int tid = threadIdx.x, lane = tid & 63, wave = tid >> 6;
    __shared__ float red[4];
    float v[3]; float s = 0.f;
    #pragma unroll
    for (int k = 0; k < 3; k++) { v[k] = x[base + tid + k * 256]; s += v[k]; }
    s = wred_sum(s);
    if (lane == 0) red[wave] = s;
    __syncthreads();
    float mean = (red[0] + red[1] + red[2] + red[3]) * (1.f / D_MODEL);
    __syncthreads();
    float sq = 0.f;
    #pragma unroll
    for (int k = 0; k < 3; k++) { float dd = v[k] - mean; sq += dd * dd; }
    sq = wred_sum(sq);
    if (lane == 0) red[wave] = sq;
    __syncthreads();
    float var = (red[0] + red[1] + red[2] + red[3]) * (1.f / D_MODEL);
    float rstd = rsqrtf(var + 1e-5f);
    #pragma unroll
    for (int k = 0; k < 3; k++) {
        int c = tid + k * 256;
        float o = (v[k] - mean) * rstd * g[c] + b[c];
        h[base + c] = o; hhf[base + c] = o;
        u16 w = f2bf(o);
        hbp[base + c] = w; hbs[base + c] = w;
    }
}

// ---------------------------------------------------------------------------
__global__ __launch_bounds__(256)
void transpose2_kernel(const u16* __restrict__ hb, u16* __restrict__ htp,
                       u16* __restrict__ hts)
{
    __shared__ u16 tile[32][33];
    int b = blockIdx.z;
    int d0 = blockIdx.x * 32, t0 = blockIdx.y * 32;
    int tx = threadIdx.x & 31, ty = threadIdx.x >> 5;
    long long bb = (long long)b * T_SEQ * D_MODEL;
    #pragma unroll
    for (int i = 0; i < 32; i += 8)
        tile[ty + i][tx] = hb[bb + (long long)(t0 + ty + i) * D_MODEL + d0 + tx];
    __syncthreads();
    #pragma unroll
    for (int i = 0; i < 32; i += 8) {
        long long o = bb + (long long)(d0 + ty + i) * T_SEQ + t0 + tx;
        u16 w = tile[tx][ty + i];
        htp[o] = w; hts[o] = w;
    }
}

// ---------------------------------------------------------------------------
// causal softmax, f16 in -> bf16 out, in place
// ---------------------------------------------------------------------------
__device__ __forceinline__ void softmax_row(u16* row, int len, int tid, int lane, int wave,
                                            float* red)
{
    float ev[4];
    float m = -3.0e38f;
    #pragma unroll
    for (int k = 0; k < 4; k++) {
        int s = tid + k * 256;
        if (s < len) {
            union { u16 u; _Float16 h; } cv; cv.u = row[s];
            ev[k] = (float)cv.h;
        } else ev[k] = -3.0e38f;
        m = fmaxf(m, ev[k]);
    }
    m = wred_max(m);
    if (lane == 0) red[wave] = m;
    __syncthreads();
    m = fmaxf(fmaxf(red[0], red[1]), fmaxf(red[2], red[3]));
    __syncthreads();
    float sum = 0.f;
    #pragma unroll
    for (int k = 0; k < 4; k++) {
        int s = tid + k * 256;
        float e = (s < len) ? __expf(ev[k] - m) : 0.f;
        ev[k] = e; sum += e;
    }
    sum = wred_sum(sum);
    if (lane == 0) red[wave] = sum;
    __syncthreads();
    sum = red[0] + red[1] + red[2] + red[3];
    float inv = 1.f / sum;
    #pragma unroll
    for (int k = 0; k < 4; k++)
        row[tid + k * 256] = f2bf(ev[k] * inv);
}

__global__ __launch_bounds__(256)
void softmax_kernel(u16* __restrict__ SP)
{
    int t = blockIdx.x, z = blockIdx.y;
    __shared__ float red[4];
    int tid = threadIdx.x, lane = tid & 63, wave = tid >> 6;
    softmax_row(SP + (long long)z * T_SEQ * T_SEQ + (long long)t * T_SEQ,
                t + 1, tid, lane, wave, red);
}

// seq softmax + fused coef slice (z == BATCH computes gate coefs for 4 rows)
__global__ __launch_bounds__(256)
void softmax_coef_kernel(u16* __restrict__ SP, const float* __restrict__ hhf,
                         const float* __restrict__ gw, const float* __restrict__ gb,
                         const float* __restrict__ sp, int ci,
                         float* __restrict__ coefS)
{
    int t = blockIdx.x, z = blockIdx.y;
    int tid = threadIdx.x, lane = tid & 63, wave = tid >> 6;
    if (z == BATCH) {
        int row = t * 4 + wave;
        long long base = (long long)row * D_MODEL;
        const float* g = gw + ci * D_MODEL;
        float dot = 0.f;
        #pragma unroll
        for (int k = 0; k < 12; k++) dot += hhf[base + lane + 64 * k] * g[lane + 64 * k];
        dot = wred_sum(dot);
        if (lane == 0) {
            float gate = 1.f / (1.f + __expf(-(dot + gb[ci])));
            coefS[row] = log1pf(expf(sp[ci])) * chamber_mask(ci) * gate;
        }
        return;
    }
    __shared__ float red[4];
    softmax_row(SP + (long long)z * T_SEQ * T_SEQ + (long long)t * T_SEQ,
                t + 1, tid, lane, wave, red);
}

// ---------------------------------------------------------------------------
__global__ __launch_bounds__(256)
void coef_par_kernel(const float* __restrict__ h, const float* __restrict__ gw,
                     const float* __restrict__ gb, const float* __restrict__ sp,
                     float* __restrict__ coefP)
{
    int row = blockIdx.x * 4 + (threadIdx.x >> 6);
    int lane = threadIdx.x & 63;
    long long base = (long long)row * D_MODEL;
    float hv[12];
    #pragma unroll
    for (int k = 0; k < 12; k++) hv[k] = h[base + lane + 64 * k];
    for (int ci = 0; ci < NCH; ci++) {
        const float* g = gw + ci * D_MODEL;
        float dot = 0.f;
        #pragma unroll
        for (int k = 0; k < 12; k++) dot += hv[k] * g[lane + 64 * k];
        dot = wred_sum(dot);
        if (lane == 0) {
            float gate = 1.f / (1.f + __expf(-(dot + gb[ci])));
            coefP[ci * ROWS + row] = log1pf(expf(sp[ci])) * chamber_mask(ci) * gate;
        }
    }
}

// ---------------------------------------------------------------------------
__global__ __launch_bounds__(256)
void cast4_kernel(const float4* __restrict__ in, ushort4* __restrict__ outp, int n4)
{
    int i = blockIdx.x * 256 + threadIdx.x;
    if (i < n4) {
        float4 v = in[i];
        ushort4 o;
        o.x = f2bf(v.x); o.y = f2bf(v.y); o.z = f2bf(v.z); o.w = f2bf(v.w);
        outp[i] = o;
    }
}

// ---------------------------------------------------------------------------
// final: par = sum of 7 bf16 partial slabs; e = (1-mg)*(hhf-h) + mg*par;
// out = x + rg*(LN(e)*g+b)
// ---------------------------------------------------------------------------
__global__ __launch_bounds__(256)
void final_kernel(const float* __restrict__ x, const float* __restrict__ h,
                  const float* __restrict__ hhf, const u16* __restrict__ Pp,
                  const float* __restrict__ mode_logit, const float* __restrict__ residual_gate,
                  const float* __restrict__ g, const float* __restrict__ b,
                  float* __restrict__ out)
{
    const long long RDe = (long long)ROWS * D_MODEL;
    int row = blockIdx.x;
    long long base = (long long)row * D_MODEL;
    int tid = threadIdx.x, lane = tid & 63, wave = tid >> 6;
    __shared__ float red[4];
    float mg = 1.f / (1.f + __expf(-mode_logit[0]));
    float rg = residual_gate[0];
    float e[3]; float s = 0.f;
    #pragma unroll
    for (int k = 0; k < 3; k++) {
        int c = tid + k * 256;
        float p = 0.f;
        #pragma unroll
        for (int z = 0; z < NCH; z++) p += bf2f(Pp[z * RDe + base + c]);
        float v = (1.f - mg) * (hhf[base + c] - h[base + c]) + mg * p;
        e[k] = v; s += v;
    }
    s = wred_sum(s);
    if (lane == 0) red[wave] = s;
    __syncthreads();
    float mean = (red[0] + red[1] + red[2] + red[3]) * (1.f / D_MODEL);
    __syncthreads();
    float sq = 0.f;
    #pragma unroll
    for (int k = 0; k < 3; k++) { float dd = e[k] - mean; sq += dd * dd; }
    sq = wred_sum(sq);
    if (lane == 0) red[wave] = sq;
    __syncthreads();
    float var = (red[0] + red[1] + red[2] + red[3]) * (1.f / D_MODEL);
    float rstd = rsqrtf(var + 1e-5f);
    #pragma unroll
    for (int k = 0; k < 3; k++) {
        int c = tid + k * 256;
        out[base + c] = x[base + c] + rg * ((e[k] - mean) * rstd * g[c] + b[c]);
    }
}

// ---------------------------------------------------------------------------
extern "C" void kernel_launch(void* const* d_in, const int* in_sizes, int n_in,
                              void* d_out, int out_size, void* d_ws, size_t ws_size,
                              hipStream_t stream)
{
    (void)in_sizes; (void)n_in; (void)out_size; (void)ws_size;
    const float* x             = (const float*)d_in[0];
    const float* Wq            = (const float*)d_in[1];
    const float* Wk            = (const float*)d_in[2];
    const float* gate_w        = (const float*)d_in[3];
    const float* gate_b        = (const float*)d_in[4];
    const float* scale_p       = (const float*)d_in[5];
    const float* merge_W       = (const float*)d_in[6];
    const float* mode_logit    = (const float*)d_in[7];
    const float* residual_gate = (const float*)d_in[8];
    const float* ln_pre_g      = (const float*)d_in[9];
    const float* ln_pre_b      = (const float*)d_in[10];
    const float* ln_post_g     = (const float*)d_in[11];
    const float* ln_post_b     = (const float*)d_in[12];
    float* out = (float*)d_out;

    const long long DD  = (long long)D_MODEL * D_MODEL;   // 589824
    const long long TD  = (long long)T_SEQ * D_MODEL;     // 786432
    const long long TTs = (long long)T_SEQ * T_SEQ;       // 1048576
    const long long RDe = (long long)ROWS * D_MODEL;      // 3145728

    size_t off = 0;
    char* wsb = (char*)d_ws;
    auto alloc = [&](size_t bytes) -> void* {
        void* p = wsb + off; off += (bytes + 255) & ~(size_t)255; return p;
    };
    u16*   Mtb  = (u16*)alloc((size_t)NCH * DD * 2);
    u16*   mgb  = (u16*)alloc((size_t)D_MODEL * KM * 2);
    float* h    = (float*)alloc(RDe * 4);
    float* hhf  = (float*)alloc(RDe * 4);
    u16*   hbp  = (u16*)alloc(RDe * 2);
    u16*   htp  = (u16*)alloc(RDe * 2);
    u16*   hbs  = (u16*)alloc(RDe * 2);
    u16*   hts0 = (u16*)alloc(RDe * 2);
    u16*   hts1 = (u16*)alloc(RDe * 2);
    u16*   Spar = (u16*)alloc((size_t)(NCH * BATCH) * TTs * 2);
    u16*   Sseq = (u16*)alloc((size_t)BATCH * TTs * 2);
    u16*   Upar = (u16*)alloc((size_t)NCH * RDe * 2);
    u16*   Useq = (u16*)alloc(RDe * 2);
    u16*   db   = (u16*)alloc((size_t)ROWS * KM * 2);
    float* coefP= (float*)alloc((size_t)NCH * ROWS * 4);
    float* coefS= (float*)alloc((size_t)ROWS * 4);
    // transient aliases (stream-ordered lifetimes):
    u16*   Wqb  = Spar;                 // dead before Spar written
    u16*   Wkb  = Spar + (size_t)NCH * DD;
    u16*   Pp   = Upar;                 // merge partials: Upar dead after par scores

    const float sc = 1.0f / sqrtf((float)D_MODEL);
    const int N4W = (int)((size_t)NCH * DD) / 4;
    const int N4M = (int)((size_t)D_MODEL * KM) / 4;

    ln_pre_kernel<<<ROWS, 256, 0, stream>>>(x, ln_pre_g, ln_pre_b, h, hhf, hbp, hbs);
    cast4_kernel<<<(N4W + 255) / 256, 256, 0, stream>>>((const float4*)Wq, (ushort4*)Wqb, N4W);
    cast4_kernel<<<(N4W + 255) / 256, 256, 0, stream>>>((const float4*)Wk, (ushort4*)Wkb, N4W);
    cast4_kernel<<<(N4M + 255) / 256, 256, 0, stream>>>((const float4*)merge_W, (ushort4*)mgb, N4M);
    transpose2_kernel<<<dim3(24, 32, BATCH), 256, 0, stream>>>(hbp, htp, hts0);
    coef_par_kernel<<<ROWS / 4, 256, 0, stream>>>(h, gate_w, gate_b, scale_p, coefP);

    // Mt_i[d'][d] = sum_e Wk_i[d'][e] Wq_i[d][e]   (z=7)
    gemm_nt_kernel<<<dim3(6, 6, NCH), 256, 0, stream>>>(
        Wkb, Wqb, Mtb, D_MODEL, D_MODEL, D_MODEL, D_MODEL,
        DD, 0, DD, 0, DD, 0, NCH, 1.f, 1, 0, 0, 0, 0);

    // ======================= par branch (frozen h, batched over chambers) ====
    // U_i = hbp @ Mt_i^T  (128-tile, swizzled)
    gemm_nt_kernel<<<dim3(6, 32, NCH), 256, 0, stream>>>(
        hbp, Mtb, Upar, D_MODEL, D_MODEL, D_MODEL, D_MODEL,
        0, 0, DD, 0, RDe, 0, NCH, 1.f, 1, 0, 0, 0, 0);
    // scores (64-tile, swizzled): Spar[ch*4+b] = U_ch[b] @ hbp[b]^T * sc
    gemm64_nt_kernel<<<dim3(16, 16, BATCH * NCH), 256, 0, stream>>>(
        Upar, hbp, Spar, D_MODEL, D_MODEL, D_MODEL, T_SEQ,
        TD, RDe, TD, 0, TTs, 4 * TTs, BATCH, sc, 3, 1, 0,
        nullptr, nullptr, nullptr);
    softmax_kernel<<<dim3(T_SEQ, BATCH * NCH), 256, 0, stream>>>(Spar);
    // PV + delta (mode 5): db[(b,t)][ch*768+d] = bf16(coef*(E - h))
    gemm64_nt_kernel<<<dim3(12, 16, BATCH * NCH), 256, 0, stream>>>(
        Spar, htp, nullptr, T_SEQ, T_SEQ, T_SEQ, D_MODEL,
        TTs, 4 * TTs, TD, 0, 0, 0, BATCH, 1.f, 5, 0, 1,
        coefP, h, db);
    // merge partials: Pp[ch] = d_ch @ Wm_ch^T  (K-slice per z)
    gemm_nt_kernel<<<dim3(6, 32, NCH), 256, 0, stream>>>(
        db, mgb, Pp, KM, KM, KM, D_MODEL,
        0, 0, 0, 0, RDe, 0, NCH, 1.f, 1, 0, 0, D_MODEL, D_MODEL);

    // ======================= seq branch (serial chain, 32-tile) ==============
    u16* htsCur = hts0;
    u16* htsNxt = hts1;
    for (int i = 0; i < NCH; i++) {
        // U = hbs @ Mt_i^T   (1536 blocks)
        gemm32_nt_kernel<<<dim3(12, 128, 1), 256, 0, stream>>>(
            hbs, Mtb + (long long)i * DD, Useq,
            D_MODEL, D_MODEL, D_MODEL, D_MODEL, 0, 0, 0, 1,
            1.f, 1, 0, 0, nullptr, nullptr, nullptr, nullptr);
        // scores: Sseq[b] = U[b] @ hbs[b]^T * sc, causal (2048 blocks)
        gemm32_nt_kernel<<<dim3(16, 32, BATCH), 256, 0, stream>>>(
            Useq, hbs, Sseq, D_MODEL, D_MODEL, D_MODEL, T_SEQ,
            TD, TD, TTs, BATCH, sc, 3, 1, 0,
            nullptr, nullptr, nullptr, nullptr);
        // softmax + fused gate-coef slice (z == BATCH)
        softmax_coef_kernel<<<dim3(T_SEQ, BATCH + 1), 256, 0, stream>>>(
            Sseq, hhf, gate_w, gate_b, scale_p, i, coefS);
        // PV + delta (mode 6): hh' = hh + coef*(E-hh) -> hhf, hbs, htsNxt (1536)
        gemm32_nt_kernel<<<dim3(12, 32, BATCH), 256, 0, stream>>>(
            Sseq, htsCur, nullptr, T_SEQ, T_SEQ, T_SEQ, D_MODEL,
            TTs, TD, 0, BATCH, 1.f, 6, 0, 1,
            hhf, coefS, hbs, htsNxt);
        u16* tmp = htsCur; htsCur = htsNxt; htsNxt = tmp;
    }

    final_kernel<<<ROWS, 256, 0, stream>>>(x, h, hhf, Pp, mode_logit, residual_gate,
                                           ln_post_g, ln_post_b, out);
}